// Round 1
// baseline (427.357 us; speedup 1.0000x reference)
//
#include <hip/hip_runtime.h>

namespace {
constexpr int S_LEN = 512;
constexpr int BATCH = 1024;
constexpr int TAG = 64;
constexpr int START_IDX = 0;
constexpr int END_IDX = 1;
constexpr float NEG_INF = -10000.0f;
constexpr int PD = 8;  // prefetch depth (steps ahead); 2 VGPRs per step of depth

typedef float v2f __attribute__((ext_vector_type(2)));
typedef float v4f __attribute__((ext_vector_type(4)));
}

// One wave (64 lanes) per batch; lane = destination tag j.
// alpha recurrence: new_alpha[j] = feat[s,b,j] + M + log( sum_i exp(alpha[i]-M) * E[j,i] )
// E[j,i] = exp(trans[j,i]) held in 32 v2f VGPRs per lane (row j).
__global__ __launch_bounds__(64) void crf_fwd_kernel(
    const float* __restrict__ feats,   // [S, B, T]
    const float* __restrict__ mask,    // [S, B]
    const float* __restrict__ trans,   // [T, T]
    float* __restrict__ out) {         // [B]
  const int b = blockIdx.x;
  const int lane = threadIdx.x;  // tag j

  __shared__ float p_lds[TAG];

  // ---- one-time: E row j into registers (exp of transition row) ----
  v2f E[TAG / 2];
  {
    const float* row = trans + lane * TAG;
#pragma unroll
    for (int k = 0; k < TAG / 4; ++k) {
      v4f tv;
      __builtin_memcpy(&tv, row + 4 * k, sizeof(v4f));
      v2f e0 = {__expf(tv.x), __expf(tv.y)};   // exp(-10000) underflows to 0 (no NaN)
      v2f e1 = {__expf(tv.z), __expf(tv.w)};
      E[2 * k] = e0;
      E[2 * k + 1] = e1;
    }
  }

  float alpha = (lane == START_IDX) ? 0.0f : NEG_INF;
  float hatM = 0.0f;  // exact max of initial alpha; thereafter anchor = alpha[lane 2]

  const float* fptr = feats + (size_t)b * TAG + lane;
  const float* mptr = mask + b;

  // ---- prefetch ring: feat[s,b,lane] is ONE float per lane per step ----
  float fbuf[PD], mbuf[PD];
#pragma unroll
  for (int d = 0; d < PD; ++d) {
    fbuf[d] = fptr[(size_t)d * (BATCH * TAG)];
    mbuf[d] = mptr[(size_t)d * BATCH];
  }

  for (int sb = 0; sb < S_LEN; sb += PD) {
#pragma unroll
    for (int d = 0; d < PD; ++d) {
      const float fcur = fbuf[d];
      const float mcur = mbuf[d];
      // mask = (s < lens[b]) is monotone non-increasing in s -> safe to stop.
      if (mcur == 0.0f) goto fin;

      int sp = sb + d + PD;
      sp = (sp < S_LEN) ? sp : (S_LEN - 1);  // clamp: harmless re-read of last row
      fbuf[d] = fptr[(size_t)sp * (BATCH * TAG)];
      mbuf[d] = mptr[(size_t)sp * BATCH];

      // p_i = exp(alpha_i - M̂); alpha==-inf -> 0, never NaN (hatM always finite)
      const float p = __expf(alpha - hatM);
      p_lds[lane] = p;
      __builtin_amdgcn_wave_barrier();  // keep reads below the write; lgkmcnt wait is
                                        // compiler-inserted (single-wave block: no s_barrier,
                                        // so the global prefetches stay in flight)

      v2f acc0 = {0.f, 0.f}, acc1 = {0.f, 0.f}, acc2 = {0.f, 0.f}, acc3 = {0.f, 0.f};
#pragma unroll
      for (int k = 0; k < TAG / 8; ++k) {
        v2f p0, p1, p2, p3;  // broadcast reads (all lanes same addr): conflict-free
        __builtin_memcpy(&p0, p_lds + 8 * k + 0, sizeof(v2f));
        __builtin_memcpy(&p1, p_lds + 8 * k + 2, sizeof(v2f));
        __builtin_memcpy(&p2, p_lds + 8 * k + 4, sizeof(v2f));
        __builtin_memcpy(&p3, p_lds + 8 * k + 6, sizeof(v2f));
        acc0 += p0 * E[4 * k + 0];  // -> v_pk_fma_f32
        acc1 += p1 * E[4 * k + 1];
        acc2 += p2 * E[4 * k + 2];
        acc3 += p3 * E[4 * k + 3];
      }
      const v2f accT = (acc0 + acc1) + (acc2 + acc3);
      const float t = accT.x + accT.y;  // t >= 0; t==0 only for tag 0 -> log -> -inf (ok)

      alpha = fcur + hatM + __logf(t);
      // next anchor: tag 2's alpha (finite for all s>=1; spread |alpha_j - alpha_2| << 88)
      hatM = __uint_as_float(__builtin_amdgcn_readlane(__float_as_uint(alpha), 2));
      __builtin_amdgcn_wave_barrier();  // WAR: next ds_write after this iter's ds_reads
    }
  }
fin:
  // ---- epilogue: out[b] = logsumexp_j(alpha_j + trans[END, j]) with exact max ----
  {
    const float a = alpha + trans[END_IDX * TAG + lane];
    float mx = a;
#pragma unroll
    for (int off = 32; off >= 1; off >>= 1) mx = fmaxf(mx, __shfl_xor(mx, off, 64));
    float e = __expf(a - mx);  // mx finite (tag 2 finite), no NaN
#pragma unroll
    for (int off = 32; off >= 1; off >>= 1) e += __shfl_xor(e, off, 64);
    if (lane == 0) out[b] = mx + __logf(e);
  }
}

extern "C" void kernel_launch(void* const* d_in, const int* in_sizes, int n_in,
                              void* d_out, int out_size, void* d_ws, size_t ws_size,
                              hipStream_t stream) {
  const float* feats = (const float*)d_in[0];
  const float* mask = (const float*)d_in[1];
  const float* trans = (const float*)d_in[2];
  float* out = (float*)d_out;
  crf_fwd_kernel<<<dim3(BATCH), dim3(64), 0, stream>>>(feats, mask, trans, out);
}